// Round 2
// baseline (176.612 us; speedup 1.0000x reference)
//
#include <hip/hip_runtime.h>

#define NX 2048      // pivotal (source) nodes
#define NC 16        // feature channels

__global__ __launch_bounds__(256) void knn_interp_kernel(
    const float* __restrict__ x,      // [NX, NC]
    const float* __restrict__ pos_x,  // [NX, 3]
    const float* __restrict__ pos_y,  // [NY, 3]
    float* __restrict__ out,          // [NY, NC]
    int ny)
{
    // (px, py, pz, ||p||^2) per candidate — 32 KB LDS, wave-uniform broadcast reads
    __shared__ float4 sp[NX];

    for (int j = threadIdx.x; j < NX; j += blockDim.x) {
        const float px = pos_x[j * 3 + 0];
        const float py = pos_x[j * 3 + 1];
        const float pz = pos_x[j * 3 + 2];
        // numpy semantics: squares rounded separately, sequential sum, NO fma
        const float sx = __fadd_rn(__fadd_rn(__fmul_rn(px, px), __fmul_rn(py, py)),
                                   __fmul_rn(pz, pz));
        sp[j] = make_float4(px, py, pz, sx);
    }
    __syncthreads();

    const int q = blockIdx.x * blockDim.x + threadIdx.x;
    if (q >= ny) return;

    const float y0 = pos_y[q * 3 + 0];
    const float y1 = pos_y[q * 3 + 1];
    const float y2 = pos_y[q * 3 + 2];
    const float sy = __fadd_rn(__fadd_rn(__fmul_rn(y0, y0), __fmul_rn(y1, y1)),
                               __fmul_rn(y2, y2));

    float b0 = 1e30f, b1 = 1e30f, b2 = 1e30f;  // best expanded-form d2, sorted
    int   i0 = 0,     i1 = 0,     i2 = 0;

    #pragma unroll 4
    for (int j = 0; j < NX; ++j) {
        const float4 p = sp[j];
        // BLAS sgemm K-loop semantics: acc = fma(a_k, b_k, acc), k ascending, acc0 = a0*b0
        const float dot = __fmaf_rn(y2, p.z, __fmaf_rn(y1, p.y, __fmul_rn(y0, p.x)));
        // d2 = (sy + sx) - 2*dot ; 2*dot is exact (power of two)
        const float d = __fsub_rn(__fadd_rn(sy, p.w), __fmul_rn(2.0f, dot));
        // strict < keeps earlier index on equal bits (matches top_k stability)
        if (d < b2) {
            if (d < b1) {
                b2 = b1; i2 = i1;
                if (d < b0) {
                    b1 = b0; i1 = i0;
                    b0 = d;  i0 = j;
                } else {
                    b1 = d; i1 = j;
                }
            } else {
                b2 = d; i2 = j;
            }
        }
    }

    // exact squared distance on the selected neighbors (reference recomputes
    // diff-form sq after selection), numpy rounding: no fma, sequential sum
    float w[3];
    const int idx[3] = { i0, i1, i2 };
    #pragma unroll
    for (int t = 0; t < 3; ++t) {
        const float4 p = sp[idx[t]];
        const float dx = __fsub_rn(p.x, y0);
        const float dy = __fsub_rn(p.y, y1);
        const float dz = __fsub_rn(p.z, y2);
        const float sq = __fadd_rn(__fadd_rn(__fmul_rn(dx, dx), __fmul_rn(dy, dy)),
                                   __fmul_rn(dz, dz));
        w[t] = 1.0f / fmaxf(sq, 1e-16f);
    }
    const float den = __fadd_rn(__fadd_rn(w[0], w[1]), w[2]);
    const float inv_den = 1.0f / den;

    // gather features (x rows are 64 B = 4 float4s) and write output
    const float4* x4 = (const float4*)x;
    float4* out4 = (float4*)out;
    #pragma unroll
    for (int t = 0; t < 4; ++t) {
        const float4 a = x4[i0 * 4 + t];
        const float4 b = x4[i1 * 4 + t];
        const float4 c = x4[i2 * 4 + t];
        float4 r;
        r.x = (w[0] * a.x + w[1] * b.x + w[2] * c.x) * inv_den;
        r.y = (w[0] * a.y + w[1] * b.y + w[2] * c.y) * inv_den;
        r.z = (w[0] * a.z + w[1] * b.z + w[2] * c.z) * inv_den;
        r.w = (w[0] * a.w + w[1] * b.w + w[2] * c.w) * inv_den;
        out4[q * 4 + t] = r;
    }
}

extern "C" void kernel_launch(void* const* d_in, const int* in_sizes, int n_in,
                              void* d_out, int out_size, void* d_ws, size_t ws_size,
                              hipStream_t stream) {
    const float* x     = (const float*)d_in[0];  // [2048, 16]
    const float* pos_x = (const float*)d_in[1];  // [2048, 3]
    const float* pos_y = (const float*)d_in[2];  // [65536, 3]
    // d_in[3] is k (==3), hardcoded

    float* out = (float*)d_out;
    const int ny = in_sizes[2] / 3;  // 65536

    const int block = 256;
    const int grid = (ny + block - 1) / block;
    knn_interp_kernel<<<grid, block, 0, stream>>>(x, pos_x, pos_y, out, ny);
}

// Round 3
// 54.999 us; speedup vs baseline: 3.2112x; 3.2112x over previous
//
#include <hip/hip_runtime.h>

#define NX 2048      // pivotal (source) nodes
#define NC 16        // feature channels
#define SEG 8        // threads (segments) per query
#define BLOCK 512    // 8 waves, 64 queries per block
#define QPB (BLOCK / SEG)

// insert (d,i) into sorted triple with lexicographic (d, idx) order
// == jax.lax.top_k ordering: smaller d2 first, ties -> lower index
__device__ __forceinline__ void insert_pair(float d, int i,
                                            float& b0, float& b1, float& b2,
                                            int& i0, int& i1, int& i2) {
    const bool lt2 = (d < b2) || (d == b2 && i < i2);
    const bool lt1 = (d < b1) || (d == b1 && i < i1);
    const bool lt0 = (d < b0) || (d == b0 && i < i0);
    b2 = lt1 ? b1 : (lt2 ? d : b2);  i2 = lt1 ? i1 : (lt2 ? i : i2);
    b1 = lt0 ? b0 : (lt1 ? d : b1);  i1 = lt0 ? i0 : (lt1 ? i : i1);
    b0 = lt0 ? d  : b0;              i0 = lt0 ? i  : i0;
}

__global__ __launch_bounds__(BLOCK, 8) void knn_interp_kernel(
    const float* __restrict__ x,      // [NX, NC]
    const float* __restrict__ pos_x,  // [NX, 3]
    const float* __restrict__ pos_y,  // [NY, 3]
    float* __restrict__ out,          // [NY, NC]
    int ny)
{
    // (px, py, pz, ||p||^2) per candidate — 32 KB LDS
    __shared__ float4 sp[NX];

    for (int j = threadIdx.x; j < NX; j += BLOCK) {
        const float px = pos_x[j * 3 + 0];
        const float py = pos_x[j * 3 + 1];
        const float pz = pos_x[j * 3 + 2];
        // numpy semantics: squares rounded separately, sequential sum, NO fma
        const float sx = __fadd_rn(__fadd_rn(__fmul_rn(px, px), __fmul_rn(py, py)),
                                   __fmul_rn(pz, pz));
        sp[j] = make_float4(px, py, pz, sx);
    }
    __syncthreads();

    const int s = threadIdx.x & (SEG - 1);            // segment within query
    const int q = blockIdx.x * QPB + (threadIdx.x >> 3);
    if (q >= ny) return;

    const float y0 = pos_y[q * 3 + 0];
    const float y1 = pos_y[q * 3 + 1];
    const float y2 = pos_y[q * 3 + 2];
    const float sy = __fadd_rn(__fadd_rn(__fmul_rn(y0, y0), __fmul_rn(y1, y1)),
                               __fmul_rn(y2, y2));

    float b0 = 1e30f, b1 = 1e30f, b2 = 1e30f;  // best expanded-form d2, sorted
    int   i0 = 0,     i1 = 0,     i2 = 0;

    // each thread scans candidates c = 8t + s (ascending -> strict < keeps
    // lowest index on bit-equal ties within the segment)
    #pragma unroll 2
    for (int t = 0; t < NX / SEG; ++t) {
        const int c = (t << 3) | s;
        const float4 p = sp[c];
        // identical numerics to the passing round-2 kernel:
        const float dot = __fmaf_rn(y2, p.z, __fmaf_rn(y1, p.y, __fmul_rn(y0, p.x)));
        const float d = __fsub_rn(__fadd_rn(sy, p.w), __fmul_rn(2.0f, dot));
        if (d < b2) {
            if (d < b1) {
                b2 = b1; i2 = i1;
                if (d < b0) {
                    b1 = b0; i1 = i0;
                    b0 = d;  i0 = c;
                } else {
                    b1 = d; i1 = c;
                }
            } else {
                b2 = d; i2 = c;
            }
        }
    }

    // butterfly merge across the 8 segments: every lane ends with the global
    // top-3 (lexicographic (d2, idx) order == top_k semantics)
    #pragma unroll
    for (int mask = 1; mask < SEG; mask <<= 1) {
        const float r0 = __shfl_xor(b0, mask);
        const float r1 = __shfl_xor(b1, mask);
        const float r2 = __shfl_xor(b2, mask);
        const int   j0 = __shfl_xor(i0, mask);
        const int   j1 = __shfl_xor(i1, mask);
        const int   j2 = __shfl_xor(i2, mask);
        insert_pair(r0, j0, b0, b1, b2, i0, i1, i2);
        insert_pair(r1, j1, b0, b1, b2, i0, i1, i2);
        insert_pair(r2, j2, b0, b1, b2, i0, i1, i2);
    }

    // exact squared distance on selected neighbors (numpy rounding: no fma)
    float w[3];
    const int idx[3] = { i0, i1, i2 };
    #pragma unroll
    for (int t = 0; t < 3; ++t) {
        const float4 p = sp[idx[t]];
        const float dx = __fsub_rn(p.x, y0);
        const float dy = __fsub_rn(p.y, y1);
        const float dz = __fsub_rn(p.z, y2);
        const float sq = __fadd_rn(__fadd_rn(__fmul_rn(dx, dx), __fmul_rn(dy, dy)),
                                   __fmul_rn(dz, dz));
        w[t] = 1.0f / fmaxf(sq, 1e-16f);
    }
    const float inv_den = 1.0f / __fadd_rn(__fadd_rn(w[0], w[1]), w[2]);

    // each lane handles 2 of the 16 channels: ch = 2s, 2s+1
    const float2* x2 = (const float2*)x;   // row stride = 8 float2
    const float2 a = x2[i0 * 8 + s];
    const float2 b = x2[i1 * 8 + s];
    const float2 c = x2[i2 * 8 + s];
    float2 r;
    r.x = (w[0] * a.x + w[1] * b.x + w[2] * c.x) * inv_den;
    r.y = (w[0] * a.y + w[1] * b.y + w[2] * c.y) * inv_den;
    ((float2*)out)[q * 8 + s] = r;
}

extern "C" void kernel_launch(void* const* d_in, const int* in_sizes, int n_in,
                              void* d_out, int out_size, void* d_ws, size_t ws_size,
                              hipStream_t stream) {
    const float* x     = (const float*)d_in[0];  // [2048, 16]
    const float* pos_x = (const float*)d_in[1];  // [2048, 3]
    const float* pos_y = (const float*)d_in[2];  // [65536, 3]
    // d_in[3] is k (==3), hardcoded

    float* out = (float*)d_out;
    const int ny = in_sizes[2] / 3;  // 65536

    const int grid = (ny + QPB - 1) / QPB;
    knn_interp_kernel<<<grid, BLOCK, 0, stream>>>(x, pos_x, pos_y, out, ny);
}

// Round 5
// 51.083 us; speedup vs baseline: 3.4574x; 1.0767x over previous
//
#include <hip/hip_runtime.h>
#include <stdint.h>

#define NXP   2048   // pivotal (source) nodes
#define NC    16     // feature channels
#define GD    8      // grid cells per axis
#define NCELL (GD*GD*GD)   // 512 == BLOCK
#define BLOCK 512
#define SEG   4      // lanes per query
#define QPB   (BLOCK / SEG)   // 128 queries per block

// cell coordinate from position in [0,1)
__device__ __forceinline__ int cell_of(float v) {
    int c = (int)(v * (float)GD);
    c = c > GD - 1 ? GD - 1 : c;
    return c < 0 ? 0 : c;
}

// monotone map: float -> uint32 preserving order (handles negatives)
__device__ __forceinline__ uint32_t mono(float d) {
    uint32_t b = __float_as_uint(d);
    return b ^ (uint32_t)(((int32_t)b >> 31) | 0x80000000);
}
__device__ __forceinline__ float unmono(uint32_t m) {
    uint32_t b = (m & 0x80000000u) ? (m ^ 0x80000000u) : ~m;
    return __uint_as_float(b);
}

// IDEMPOTENT insert: key = (mono(d2) << 32) | orig_idx. Equality <=> same
// candidate (index unique), so dedup makes re-insertion/merge-of-overlapping-
// triples safe. Lex (d2, idx) order == jax.lax.top_k ordering.
__device__ __forceinline__ void ins_key(uint64_t k, uint64_t& b0, uint64_t& b1, uint64_t& b2) {
    if (k == b0 || k == b1 || k == b2) return;
    const bool lt0 = k < b0, lt1 = k < b1, lt2 = k < b2;
    b2 = lt1 ? b1 : (lt2 ? k : b2);
    b1 = lt0 ? b0 : (lt1 ? k : b1);
    b0 = lt0 ? k  : b0;
}

__device__ __forceinline__ uint64_t shfl_xor_u64(uint64_t v, int mask) {
    const int lo = __shfl_xor((int)(uint32_t)v, mask);
    const int hi = __shfl_xor((int)(uint32_t)(v >> 32), mask);
    return ((uint64_t)(uint32_t)hi << 32) | (uint32_t)lo;
}

// butterfly merge across the SEG-lane group; all lanes end identical
__device__ __forceinline__ void merge_group(uint64_t& b0, uint64_t& b1, uint64_t& b2) {
    #pragma unroll
    for (int mask = 1; mask < SEG; mask <<= 1) {
        const uint64_t r0 = shfl_xor_u64(b0, mask);
        const uint64_t r1 = shfl_xor_u64(b1, mask);
        const uint64_t r2 = shfl_xor_u64(b2, mask);
        ins_key(r0, b0, b1, b2);
        ins_key(r1, b0, b1, b2);
        ins_key(r2, b0, b1, b2);
    }
}

__global__ __launch_bounds__(BLOCK) void knn_grid_kernel(
    const float* __restrict__ x,      // [NXP, NC]
    const float* __restrict__ pos_x,  // [NXP, 3]
    const float* __restrict__ pos_y,  // [NY, 3]
    float* __restrict__ out,          // [NY, NC]
    int ny)
{
    __shared__ float4 spt[NXP];        // cell-sorted (px,py,pz,||p||^2)  32 KB
    __shared__ int    sidx[NXP];       // original index                   8 KB
    __shared__ int    cstart[NCELL+1]; // cell -> slot range
    __shared__ int    sA[NCELL];
    __shared__ int    sB[NCELL];
    __shared__ int    cur[NCELL];

    const int t = threadIdx.x;

    // ================= grid build (per block, 2048 pts) =================
    sA[t] = 0;
    __syncthreads();

    // 4 points per thread via 3 coalesced float4 loads (12 floats)
    const float4* px4 = (const float4*)pos_x;
    const float4 v0 = px4[t*3+0], v1 = px4[t*3+1], v2 = px4[t*3+2];
    const float pxx[4] = {v0.x, v0.w, v1.z, v2.y};
    const float pyy[4] = {v0.y, v1.x, v1.w, v2.z};
    const float pzz[4] = {v0.z, v1.y, v2.x, v2.w};
    int cc[4];
    #pragma unroll
    for (int i = 0; i < 4; ++i) {
        cc[i] = (cell_of(pzz[i]) * GD + cell_of(pyy[i])) * GD + cell_of(pxx[i]);
        atomicAdd(&sA[cc[i]], 1);
    }
    __syncthreads();

    // inclusive prefix sum over 512 counts (Hillis-Steele, ping-pong)
    int* src = sA; int* dst = sB;
    for (int off = 1; off < NCELL; off <<= 1) {
        dst[t] = src[t] + (t >= off ? src[t - off] : 0);
        __syncthreads();
        int* tmp = src; src = dst; dst = tmp;
    }
    if (t == 0) cstart[0] = 0;
    cstart[t + 1] = src[t];
    cur[t] = (t == 0) ? 0 : src[t - 1];
    __syncthreads();

    // scatter into cell-sorted order (order nondeterministic; output is
    // order-independent because selection keys carry the original index)
    #pragma unroll
    for (int i = 0; i < 4; ++i) {
        const int p = t * 4 + i;
        const int pos = atomicAdd(&cur[cc[i]], 1);
        // ||p||^2 with reference numerics: separate squares, sequential sum
        const float sx = __fadd_rn(__fadd_rn(__fmul_rn(pxx[i], pxx[i]),
                                             __fmul_rn(pyy[i], pyy[i])),
                                   __fmul_rn(pzz[i], pzz[i]));
        spt[pos] = make_float4(pxx[i], pyy[i], pzz[i], sx);
        sidx[pos] = p;
    }
    __syncthreads();

    // ================= query phase: SEG lanes per query =================
    const int s = t & (SEG - 1);
    const int q = blockIdx.x * QPB + (t >> 2);
    if (q >= ny) return;

    const float y0 = pos_y[q*3+0], y1 = pos_y[q*3+1], y2 = pos_y[q*3+2];
    const float sy = __fadd_rn(__fadd_rn(__fmul_rn(y0, y0), __fmul_rn(y1, y1)),
                               __fmul_rn(y2, y2));
    const int cx = cell_of(y0), cy = cell_of(y1), cz = cell_of(y2);

    uint64_t b0 = ~0ull, b1 = ~0ull, b2 = ~0ull;

    // candidate evaluation: identical rounding to the passing round-2 kernel
    // (fmaf(-2,dot,sy+sx) == fsub(fadd(sy,sx), fmul(2,dot)) since 2*dot exact)
#define EVAL_PT(P)                                                              \
    {                                                                           \
        const float4 pt = spt[P];                                               \
        const int oi = sidx[P];                                                 \
        const float dot = __fmaf_rn(y2, pt.z,                                   \
                          __fmaf_rn(y1, pt.y, __fmul_rn(y0, pt.x)));            \
        const float d = __fmaf_rn(-2.0f, dot, __fadd_rn(sy, pt.w));             \
        const uint64_t kk = ((uint64_t)mono(d) << 32) | (uint32_t)oi;           \
        ins_key(kk, b0, b1, b2);                                                \
    }

    // rings 0+1: the 3x3x3 cell cube, split across the SEG lanes
    for (int i = s; i < 27; i += SEG) {
        const int dz = i / 9, rem = i - dz * 9, dy = rem / 3, dx = rem - dy * 3;
        const int ux = cx + dx - 1, uy = cy + dy - 1, uz = cz + dz - 1;
        const bool valid = ((unsigned)ux < (unsigned)GD) &
                           ((unsigned)uy < (unsigned)GD) &
                           ((unsigned)uz < (unsigned)GD);
        const int c = valid ? (uz * GD + uy) * GD + ux : 0;
        const int st = cstart[c];
        int en = cstart[c + 1];
        if (!valid) en = st;
        for (int p = st; p < en; ++p) EVAL_PT(p)
    }
    merge_group(b0, b1, b2);

    // stop bound: ring-2 cells are >= h = 0.125 away -> exact d2 >= 0.015625.
    // margin 1e-4 >> |expanded-d2 - exact-d2| (<= ~4e-6) -> superset is safe.
    {
        uint32_t m2 = (uint32_t)(b2 >> 32);
        bool have3 = (m2 != 0xFFFFFFFFu);
        float b2d = unmono(m2);
        if (!(have3 && (0.015625f > b2d + 1e-4f))) {
            // ring 2: shell of the 5x5x5 cube
            for (int i = s; i < 125; i += SEG) {
                const int dz = i / 25, rem = i - dz * 25, dy = rem / 5, dx = rem - dy * 5;
                const int adx = abs(dx - 2), ady = abs(dy - 2), adz = abs(dz - 2);
                const bool shell = (adx == 2) | (ady == 2) | (adz == 2);
                const int ux = cx + dx - 2, uy = cy + dy - 2, uz = cz + dz - 2;
                const bool valid = shell &
                                   ((unsigned)ux < (unsigned)GD) &
                                   ((unsigned)uy < (unsigned)GD) &
                                   ((unsigned)uz < (unsigned)GD);
                const int c = valid ? (uz * GD + uy) * GD + ux : 0;
                const int st = cstart[c];
                int en = cstart[c + 1];
                if (!valid) en = st;
                for (int p = st; p < en; ++p) EVAL_PT(p)
            }
            merge_group(b0, b1, b2);

            // ring >=3 is >= 2h = 0.25 away -> d2 >= 0.0625; else brute-force.
            m2 = (uint32_t)(b2 >> 32);
            have3 = (m2 != 0xFFFFFFFFu);
            b2d = unmono(m2);
            if (!(have3 && (0.0625f > b2d + 1e-4f))) {
                for (int p = s; p < NXP; p += SEG) EVAL_PT(p)  // dedup -> safe
                merge_group(b0, b1, b2);
            }
        }
    }
#undef EVAL_PT

    // ================= epilogue (all SEG lanes hold identical top-3) =======
    const int j[3] = { (int)(uint32_t)b0, (int)(uint32_t)b1, (int)(uint32_t)b2 };
    float w[3];
    #pragma unroll
    for (int i = 0; i < 3; ++i) {
        const int jj = j[i];
        const float ax = pos_x[jj*3+0], ay = pos_x[jj*3+1], az = pos_x[jj*3+2];
        const float dx = __fsub_rn(ax, y0);
        const float dy = __fsub_rn(ay, y1);
        const float dz = __fsub_rn(az, y2);
        const float sq = __fadd_rn(__fadd_rn(__fmul_rn(dx, dx), __fmul_rn(dy, dy)),
                                   __fmul_rn(dz, dz));
        w[i] = 1.0f / fmaxf(sq, 1e-16f);
    }
    const float inv_den = 1.0f / __fadd_rn(__fadd_rn(w[0], w[1]), w[2]);

    // lane s handles channels [4s, 4s+4): one float4 per neighbor
    const float4* x4 = (const float4*)x;
    float4* o4 = (float4*)out;
    const float4 a = x4[j[0]*4 + s];
    const float4 b = x4[j[1]*4 + s];
    const float4 c = x4[j[2]*4 + s];
    float4 r;
    r.x = (w[0]*a.x + w[1]*b.x + w[2]*c.x) * inv_den;
    r.y = (w[0]*a.y + w[1]*b.y + w[2]*c.y) * inv_den;
    r.z = (w[0]*a.z + w[1]*b.z + w[2]*c.z) * inv_den;
    r.w = (w[0]*a.w + w[1]*b.w + w[2]*c.w) * inv_den;
    o4[q*4 + s] = r;
}

extern "C" void kernel_launch(void* const* d_in, const int* in_sizes, int n_in,
                              void* d_out, int out_size, void* d_ws, size_t ws_size,
                              hipStream_t stream) {
    const float* x     = (const float*)d_in[0];  // [2048, 16]
    const float* pos_x = (const float*)d_in[1];  // [2048, 3]
    const float* pos_y = (const float*)d_in[2];  // [65536, 3]
    // d_in[3] is k (==3), hardcoded

    float* out = (float*)d_out;
    const int ny = in_sizes[2] / 3;  // 65536

    const int grid = (ny + QPB - 1) / QPB;
    knn_grid_kernel<<<grid, BLOCK, 0, stream>>>(x, pos_x, pos_y, out, ny);
}

// Round 6
// 33.960 us; speedup vs baseline: 5.2005x; 1.5042x over previous
//
#include <hip/hip_runtime.h>
#include <stdint.h>

#define NXP   2048   // pivotal (source) nodes
#define NC    16     // feature channels
#define GD    8      // grid cells per axis
#define NCELL (GD*GD*GD)   // 512
#define BBLK  512    // build-kernel block
#define QBLK  512    // query-kernel block (8 waves)
#define SEG   8      // lanes per query
#define QPB   (QBLK / SEG)   // 64 queries per block

// d_ws layout (bytes)
#define WS_SPT   0        // float4[2048]  (px,py,pz,||p||^2) cell-sorted, 32768 B
#define WS_SIDX  32768    // int[2048]     original index,                  8192 B
#define WS_CST   40960    // int[513]      cell -> slot range,              2052 B

__device__ __forceinline__ int cell_of(float v) {
    int c = (int)(v * (float)GD);
    c = c > GD - 1 ? GD - 1 : c;
    return c < 0 ? 0 : c;
}

// monotone map: float -> uint32 preserving order (handles negatives)
__device__ __forceinline__ uint32_t mono(float d) {
    uint32_t b = __float_as_uint(d);
    return b ^ (uint32_t)(((int32_t)b >> 31) | 0x80000000);
}
__device__ __forceinline__ float unmono(uint32_t m) {
    uint32_t b = (m & 0x80000000u) ? (m ^ 0x80000000u) : ~m;
    return __uint_as_float(b);
}

// fast insert: caller guarantees k < b2 and k not already present
__device__ __forceinline__ void ins_fast(uint64_t k, uint64_t& b0, uint64_t& b1, uint64_t& b2) {
    const bool lt0 = k < b0, lt1 = k < b1;
    b2 = lt1 ? b1 : k;
    b1 = lt0 ? b0 : (lt1 ? k : b1);
    b0 = lt0 ? k  : b0;
}

// idempotent insert (dedup on full key; index uniqueness => equality <=> same pt)
__device__ __forceinline__ void ins_dedup(uint64_t k, uint64_t& b0, uint64_t& b1, uint64_t& b2) {
    if (k == b0 || k == b1 || k == b2) return;
    const bool lt0 = k < b0, lt1 = k < b1, lt2 = k < b2;
    b2 = lt1 ? b1 : (lt2 ? k : b2);
    b1 = lt0 ? b0 : (lt1 ? k : b1);
    b0 = lt0 ? k  : b0;
}

__device__ __forceinline__ uint64_t shfl_xor_u64(uint64_t v, int mask) {
    const int lo = __shfl_xor((int)(uint32_t)v, mask);
    const int hi = __shfl_xor((int)(uint32_t)(v >> 32), mask);
    return ((uint64_t)(uint32_t)hi << 32) | (uint32_t)lo;
}

// butterfly merge across the 8-lane group; all lanes end identical
__device__ __forceinline__ void merge_group(uint64_t& b0, uint64_t& b1, uint64_t& b2) {
    #pragma unroll
    for (int mask = 1; mask < SEG; mask <<= 1) {
        const uint64_t r0 = shfl_xor_u64(b0, mask);
        const uint64_t r1 = shfl_xor_u64(b1, mask);
        const uint64_t r2 = shfl_xor_u64(b2, mask);
        ins_dedup(r0, b0, b1, b2);
        ins_dedup(r1, b0, b1, b2);
        ins_dedup(r2, b0, b1, b2);
    }
}

// =============== kernel 1: build cell-sorted grid into d_ws ===============
__global__ __launch_bounds__(BBLK) void build_grid(
    const float* __restrict__ pos_x,
    float4* __restrict__ wspt, int* __restrict__ wsidx, int* __restrict__ wcstart)
{
    __shared__ int sA[NCELL];
    __shared__ int sB[NCELL];
    __shared__ int cur[NCELL];
    const int t = threadIdx.x;

    sA[t] = 0;
    __syncthreads();

    // 4 points per thread via 3 coalesced float4 loads
    const float4* px4 = (const float4*)pos_x;
    const float4 v0 = px4[t*3+0], v1 = px4[t*3+1], v2 = px4[t*3+2];
    const float pxx[4] = {v0.x, v0.w, v1.z, v2.y};
    const float pyy[4] = {v0.y, v1.x, v1.w, v2.z};
    const float pzz[4] = {v0.z, v1.y, v2.x, v2.w};
    int cc[4];
    #pragma unroll
    for (int i = 0; i < 4; ++i) {
        cc[i] = (cell_of(pzz[i]) * GD + cell_of(pyy[i])) * GD + cell_of(pxx[i]);
        atomicAdd(&sA[cc[i]], 1);
    }
    __syncthreads();

    // inclusive prefix sum over 512 counts (Hillis-Steele, ping-pong)
    int* src = sA; int* dst = sB;
    for (int off = 1; off < NCELL; off <<= 1) {
        dst[t] = src[t] + (t >= off ? src[t - off] : 0);
        __syncthreads();
        int* tmp = src; src = dst; dst = tmp;
    }
    wcstart[t + 1] = src[t];
    if (t == 0) wcstart[0] = 0;
    cur[t] = (t == 0) ? 0 : src[t - 1];
    __syncthreads();

    // scatter (order nondeterministic; selection is order-independent since
    // keys carry the original index)
    #pragma unroll
    for (int i = 0; i < 4; ++i) {
        const int p = t * 4 + i;
        const int pos = atomicAdd(&cur[cc[i]], 1);
        // ||p||^2 with reference numerics: separate squares, sequential sum
        const float sx = __fadd_rn(__fadd_rn(__fmul_rn(pxx[i], pxx[i]),
                                             __fmul_rn(pyy[i], pyy[i])),
                                   __fmul_rn(pzz[i], pzz[i]));
        wspt[pos] = make_float4(pxx[i], pyy[i], pzz[i], sx);
        wsidx[pos] = p;
    }
}

// =============== kernel 2: query ===============
__global__ __launch_bounds__(QBLK) void knn_query(
    const float* __restrict__ x,      // [NXP, NC]
    const float* __restrict__ pos_x,  // [NXP, 3]
    const float* __restrict__ pos_y,  // [NY, 3]
    const float4* __restrict__ wspt, const int* __restrict__ wsidx,
    const int* __restrict__ wcstart,
    float* __restrict__ out,          // [NY, NC]
    int ny)
{
    __shared__ float4 spt[NXP];      // 32 KB
    __shared__ int    sidx[NXP];     //  8 KB
    __shared__ int    cstart[NCELL + 1];

    const int t = threadIdx.x;

    // plain coalesced staging (no atomics, no prefix sum)
    #pragma unroll
    for (int i = t; i < NXP; i += QBLK) spt[i] = wspt[i];
    #pragma unroll
    for (int i = t; i < NXP; i += QBLK) sidx[i] = wsidx[i];
    for (int i = t; i < NCELL + 1; i += QBLK) cstart[i] = wcstart[i];
    __syncthreads();

    const int s = t & (SEG - 1);
    const int q = blockIdx.x * QPB + (t >> 3);
    if (q >= ny) return;

    const float y0 = pos_y[q*3+0], y1 = pos_y[q*3+1], y2 = pos_y[q*3+2];
    const float sy = __fadd_rn(__fadd_rn(__fmul_rn(y0, y0), __fmul_rn(y1, y1)),
                               __fmul_rn(y2, y2));
    const int cx = cell_of(y0), cy = cell_of(y1), cz = cell_of(y2);

    uint64_t b0 = ~0ull, b1 = ~0ull, b2 = ~0ull;

    // candidate d2: identical rounding to the passing round-2/3/5 kernels
#define EVAL_BODY(P, INS)                                                       \
    {                                                                           \
        const float4 pt = spt[P];                                               \
        const float dot = __fmaf_rn(y2, pt.z,                                   \
                          __fmaf_rn(y1, pt.y, __fmul_rn(y0, pt.x)));            \
        const float d = __fmaf_rn(-2.0f, dot, __fadd_rn(sy, pt.w));             \
        const uint64_t kk = ((uint64_t)mono(d) << 32) | (uint32_t)sidx[P];      \
        if (kk < b2) INS(kk, b0, b1, b2);                                       \
    }

    // ---- rings 0+1: 3x3x3 cube = 9 x-contiguous runs; 8 lanes stride a run
    const int x0 = cx - 1 < 0 ? 0 : cx - 1;
    const int x1 = cx + 1 > GD - 1 ? GD - 1 : cx + 1;
    #pragma unroll
    for (int r = 0; r < 9; ++r) {
        const int uz = cz + r / 3 - 1, uy = cy + r % 3 - 1;
        int st = 0, en = 0;
        if (((unsigned)uz < (unsigned)GD) & ((unsigned)uy < (unsigned)GD)) {
            const int cb = (uz * GD + uy) * GD;
            st = cstart[cb + x0];
            en = cstart[cb + x1 + 1];
        }
        for (int p = st + s; p < en; p += SEG) EVAL_BODY(p, ins_fast)
    }
    merge_group(b0, b1, b2);

    // stop bound: ring-2 exact d2 >= (1*h)^2 = 0.015625; expanded-form skew
    // <= ~4e-6 << 1e-4 margin, so the superset provably contains the top-3.
    {
        bool have3 = (b2 != ~0ull);
        float b2d = unmono((uint32_t)(b2 >> 32));
        if (!(have3 && (b2d + 1e-4f < 0.015625f))) {
            // ---- ring 2: shell of the 5x5x5 cube
            for (int r = 0; r < 25; ++r) {
                const int dzi = r / 5 - 2, dyi = r % 5 - 2;
                const int uz = cz + dzi, uy = cy + dyi;
                if (((unsigned)uz >= (unsigned)GD) | ((unsigned)uy >= (unsigned)GD))
                    continue;
                const int cb = (uz * GD + uy) * GD;
                if (dzi == -2 || dzi == 2 || dyi == -2 || dyi == 2) {
                    const int xa = cx - 2 < 0 ? 0 : cx - 2;
                    const int xb = cx + 2 > GD - 1 ? GD - 1 : cx + 2;
                    const int st = cstart[cb + xa], en = cstart[cb + xb + 1];
                    for (int p = st + s; p < en; p += SEG) EVAL_BODY(p, ins_fast)
                } else {
                    if (cx - 2 >= 0) {
                        const int st = cstart[cb + cx - 2], en = cstart[cb + cx - 1];
                        for (int p = st + s; p < en; p += SEG) EVAL_BODY(p, ins_fast)
                    }
                    if (cx + 2 <= GD - 1) {
                        const int st = cstart[cb + cx + 2], en = cstart[cb + cx + 3];
                        for (int p = st + s; p < en; p += SEG) EVAL_BODY(p, ins_fast)
                    }
                }
            }
            merge_group(b0, b1, b2);

            // ring >=3 exact d2 >= (2h)^2 = 0.0625; else brute-force (dedup'd)
            have3 = (b2 != ~0ull);
            b2d = unmono((uint32_t)(b2 >> 32));
            if (!(have3 && (b2d + 1e-4f < 0.0625f))) {
                for (int p = s; p < NXP; p += SEG) EVAL_BODY(p, ins_dedup)
                merge_group(b0, b1, b2);
            }
        }
    }
#undef EVAL_BODY

    // ---- epilogue (all 8 lanes hold the identical top-3)
    const int j[3] = { (int)(uint32_t)b0, (int)(uint32_t)b1, (int)(uint32_t)b2 };
    float w[3];
    #pragma unroll
    for (int i = 0; i < 3; ++i) {
        const int jj = j[i];
        const float ax = pos_x[jj*3+0], ay = pos_x[jj*3+1], az = pos_x[jj*3+2];
        const float dx = __fsub_rn(ax, y0);
        const float dy = __fsub_rn(ay, y1);
        const float dz = __fsub_rn(az, y2);
        const float sq = __fadd_rn(__fadd_rn(__fmul_rn(dx, dx), __fmul_rn(dy, dy)),
                                   __fmul_rn(dz, dz));
        w[i] = 1.0f / fmaxf(sq, 1e-16f);
    }
    const float inv_den = 1.0f / __fadd_rn(__fadd_rn(w[0], w[1]), w[2]);

    // lane s handles channels [2s, 2s+2): one float2 per neighbor (coalesced)
    const float2* x2 = (const float2*)x;   // row stride = 8 float2
    float2* o2 = (float2*)out;
    const float2 a = x2[j[0]*8 + s];
    const float2 b = x2[j[1]*8 + s];
    const float2 c = x2[j[2]*8 + s];
    float2 rr;
    rr.x = (w[0]*a.x + w[1]*b.x + w[2]*c.x) * inv_den;
    rr.y = (w[0]*a.y + w[1]*b.y + w[2]*c.y) * inv_den;
    o2[q*8 + s] = rr;
}

extern "C" void kernel_launch(void* const* d_in, const int* in_sizes, int n_in,
                              void* d_out, int out_size, void* d_ws, size_t ws_size,
                              hipStream_t stream) {
    const float* x     = (const float*)d_in[0];  // [2048, 16]
    const float* pos_x = (const float*)d_in[1];  // [2048, 3]
    const float* pos_y = (const float*)d_in[2];  // [65536, 3]
    // d_in[3] is k (==3), hardcoded

    float* out = (float*)d_out;
    const int ny = in_sizes[2] / 3;  // 65536

    float4* wspt   = (float4*)((char*)d_ws + WS_SPT);
    int*    wsidx  = (int*)   ((char*)d_ws + WS_SIDX);
    int*    wcst   = (int*)   ((char*)d_ws + WS_CST);

    build_grid<<<1, BBLK, 0, stream>>>(pos_x, wspt, wsidx, wcst);

    const int grid = (ny + QPB - 1) / QPB;
    knn_query<<<grid, QBLK, 0, stream>>>(x, pos_x, pos_y, wspt, wsidx, wcst, out, ny);
}

// Round 7
// 33.935 us; speedup vs baseline: 5.2044x; 1.0008x over previous
//
#include <hip/hip_runtime.h>
#include <stdint.h>

#define NXP   2048   // pivotal (source) nodes
#define NC    16     // feature channels
#define GD    8      // grid cells per axis
#define NCELL (GD*GD*GD)   // 512
#define BBLK  512    // build-kernel block
#define QBLK  512    // query-kernel block (8 waves)
#define SEG   8      // lanes per query
#define QPB   (QBLK / SEG)   // 64 queries per batch
#define QGRID 512    // query blocks (each does 2 batches at ny=65536)

// d_ws layout (bytes)
#define WS_SPT   0        // float4[2048]  (px,py,pz,||p||^2) cell-sorted
#define WS_SIDX  32768    // int[2048]     original index
#define WS_CST   40960    // int[513]      cell -> slot range

__device__ __forceinline__ int cell_of(float v) {
    int c = (int)(v * (float)GD);
    c = c > GD - 1 ? GD - 1 : c;
    return c < 0 ? 0 : c;
}

// monotone map: float -> uint32 preserving order (handles negatives)
__device__ __forceinline__ uint32_t mono(float d) {
    uint32_t b = __float_as_uint(d);
    return b ^ (uint32_t)(((int32_t)b >> 31) | 0x80000000);
}
__device__ __forceinline__ float unmono(uint32_t m) {
    uint32_t b = (m & 0x80000000u) ? (m ^ 0x80000000u) : ~m;
    return __uint_as_float(b);
}

// fast insert: caller guarantees k < b2 and k not already present
__device__ __forceinline__ void ins_fast(uint64_t k, uint64_t& b0, uint64_t& b1, uint64_t& b2) {
    const bool lt0 = k < b0, lt1 = k < b1;
    b2 = lt1 ? b1 : k;
    b1 = lt0 ? b0 : (lt1 ? k : b1);
    b0 = lt0 ? k  : b0;
}

// idempotent insert (dedup on full key; index uniqueness => equality <=> same pt)
__device__ __forceinline__ void ins_dedup(uint64_t k, uint64_t& b0, uint64_t& b1, uint64_t& b2) {
    if (k == b0 || k == b1 || k == b2) return;
    const bool lt0 = k < b0, lt1 = k < b1, lt2 = k < b2;
    b2 = lt1 ? b1 : (lt2 ? k : b2);
    b1 = lt0 ? b0 : (lt1 ? k : b1);
    b0 = lt0 ? k  : b0;
}

__device__ __forceinline__ uint64_t shfl_xor_u64(uint64_t v, int mask) {
    const int lo = __shfl_xor((int)(uint32_t)v, mask);
    const int hi = __shfl_xor((int)(uint32_t)(v >> 32), mask);
    return ((uint64_t)(uint32_t)hi << 32) | (uint32_t)lo;
}

// butterfly merge across the 8-lane group; all lanes end identical
__device__ __forceinline__ void merge_group(uint64_t& b0, uint64_t& b1, uint64_t& b2) {
    #pragma unroll
    for (int mask = 1; mask < SEG; mask <<= 1) {
        const uint64_t r0 = shfl_xor_u64(b0, mask);
        const uint64_t r1 = shfl_xor_u64(b1, mask);
        const uint64_t r2 = shfl_xor_u64(b2, mask);
        ins_dedup(r0, b0, b1, b2);
        ins_dedup(r1, b0, b1, b2);
        ins_dedup(r2, b0, b1, b2);
    }
}

// =============== kernel 1: build cell-sorted grid into d_ws ===============
__global__ __launch_bounds__(BBLK) void build_grid(
    const float* __restrict__ pos_x,
    float4* __restrict__ wspt, int* __restrict__ wsidx, int* __restrict__ wcstart)
{
    __shared__ int sA[NCELL];
    __shared__ int cur[NCELL];
    const int t = threadIdx.x;

    sA[t] = 0;
    __syncthreads();

    // 4 points per thread via 3 coalesced float4 loads
    const float4* px4 = (const float4*)pos_x;
    const float4 v0 = px4[t*3+0], v1 = px4[t*3+1], v2 = px4[t*3+2];
    const float pxx[4] = {v0.x, v0.w, v1.z, v2.y};
    const float pyy[4] = {v0.y, v1.x, v1.w, v2.z};
    const float pzz[4] = {v0.z, v1.y, v2.x, v2.w};
    int cc[4];
    #pragma unroll
    for (int i = 0; i < 4; ++i) {
        cc[i] = (cell_of(pzz[i]) * GD + cell_of(pyy[i])) * GD + cell_of(pxx[i]);
        atomicAdd(&sA[cc[i]], 1);
    }
    __syncthreads();

    // prefix sum over 512 counts: wave 0 only, 8 cells/lane + shfl_up scan
    if (t < 64) {
        const int base = t * 8;
        int v[8];
        int run = 0;
        #pragma unroll
        for (int i = 0; i < 8; ++i) { run += sA[base + i]; v[i] = run; }
        // exclusive wave scan of per-lane sums (width 64)
        int xs = run;
        #pragma unroll
        for (int off = 1; off < 64; off <<= 1) {
            const int y = __shfl_up(xs, off);
            if (t >= off) xs += y;
        }
        const int excl = xs - run;
        #pragma unroll
        for (int i = 0; i < 8; ++i) {
            const int inc = excl + v[i];          // inclusive prefix at cell base+i
            wcstart[base + i + 1] = inc;
            cur[base + i] = inc - sA[base + i];   // exclusive start
        }
        if (t == 0) wcstart[0] = 0;
    }
    __syncthreads();

    // scatter (order nondeterministic; selection is order-independent since
    // keys carry the original index)
    #pragma unroll
    for (int i = 0; i < 4; ++i) {
        const int p = t * 4 + i;
        const int pos = atomicAdd(&cur[cc[i]], 1);
        // ||p||^2 with reference numerics: separate squares, sequential sum
        const float sx = __fadd_rn(__fadd_rn(__fmul_rn(pxx[i], pxx[i]),
                                             __fmul_rn(pyy[i], pyy[i])),
                                   __fmul_rn(pzz[i], pzz[i]));
        wspt[pos] = make_float4(pxx[i], pyy[i], pzz[i], sx);
        wsidx[pos] = p;
    }
}

// =============== kernel 2: query (grid-stride over query batches) ===============
__global__ __launch_bounds__(QBLK) void knn_query(
    const float* __restrict__ x,      // [NXP, NC]
    const float* __restrict__ pos_x,  // [NXP, 3]
    const float* __restrict__ pos_y,  // [NY, 3]
    const float4* __restrict__ wspt, const int* __restrict__ wsidx,
    const int* __restrict__ wcstart,
    float* __restrict__ out,          // [NY, NC]
    int ny)
{
    __shared__ float4 spt[NXP];      // 32 KB
    __shared__ int    sidx[NXP];     //  8 KB
    __shared__ int    cstart[NCELL + 1];

    const int t = threadIdx.x;

    // plain coalesced staging (once per block)
    #pragma unroll
    for (int i = t; i < NXP; i += QBLK) spt[i] = wspt[i];
    #pragma unroll
    for (int i = t; i < NXP; i += QBLK) sidx[i] = wsidx[i];
    for (int i = t; i < NCELL + 1; i += QBLK) cstart[i] = wcstart[i];
    __syncthreads();

    const int s = t & (SEG - 1);
    const int nbatch = (ny + QPB - 1) / QPB;

    for (int batch = blockIdx.x; batch < nbatch; batch += gridDim.x) {
        const int q = batch * QPB + (t >> 3);
        if (q >= ny) continue;

        const float y0 = pos_y[q*3+0], y1 = pos_y[q*3+1], y2 = pos_y[q*3+2];
        const float sy = __fadd_rn(__fadd_rn(__fmul_rn(y0, y0), __fmul_rn(y1, y1)),
                                   __fmul_rn(y2, y2));
        const int cx = cell_of(y0), cy = cell_of(y1), cz = cell_of(y2);

        uint64_t b0 = ~0ull, b1 = ~0ull, b2 = ~0ull;

        // candidate d2: identical rounding to the passing round-2/3/5/6 kernels
#define EVAL_BODY(P, INS)                                                       \
        {                                                                       \
            const float4 pt = spt[P];                                           \
            const float dot = __fmaf_rn(y2, pt.z,                               \
                              __fmaf_rn(y1, pt.y, __fmul_rn(y0, pt.x)));        \
            const float d = __fmaf_rn(-2.0f, dot, __fadd_rn(sy, pt.w));         \
            const uint64_t kk = ((uint64_t)mono(d) << 32) | (uint32_t)sidx[P];  \
            if (kk < b2) INS(kk, b0, b1, b2);                                   \
        }

        // rings 0+1: 3x3x3 cube = 9 x-contiguous runs; 8 lanes stride a run
        const int x0 = cx - 1 < 0 ? 0 : cx - 1;
        const int x1 = cx + 1 > GD - 1 ? GD - 1 : cx + 1;
        #pragma unroll
        for (int r = 0; r < 9; ++r) {
            const int uz = cz + r / 3 - 1, uy = cy + r % 3 - 1;
            int st = 0, en = 0;
            if (((unsigned)uz < (unsigned)GD) & ((unsigned)uy < (unsigned)GD)) {
                const int cb = (uz * GD + uy) * GD;
                st = cstart[cb + x0];
                en = cstart[cb + x1 + 1];
            }
            for (int p = st + s; p < en; p += SEG) EVAL_BODY(p, ins_fast)
        }
        merge_group(b0, b1, b2);

        // stop bound: ring-2 exact d2 >= h^2 = 0.015625; expanded-form skew
        // <= ~4e-6 << 1e-4 margin, so the superset provably contains the top-3.
        {
            bool have3 = (b2 != ~0ull);
            float b2d = unmono((uint32_t)(b2 >> 32));
            if (!(have3 && (b2d + 1e-4f < 0.015625f))) {
                // ring 2: shell of the 5x5x5 cube
                for (int r = 0; r < 25; ++r) {
                    const int dzi = r / 5 - 2, dyi = r % 5 - 2;
                    const int uz = cz + dzi, uy = cy + dyi;
                    if (((unsigned)uz >= (unsigned)GD) | ((unsigned)uy >= (unsigned)GD))
                        continue;
                    const int cb = (uz * GD + uy) * GD;
                    if (dzi == -2 || dzi == 2 || dyi == -2 || dyi == 2) {
                        const int xa = cx - 2 < 0 ? 0 : cx - 2;
                        const int xb = cx + 2 > GD - 1 ? GD - 1 : cx + 2;
                        const int st = cstart[cb + xa], en = cstart[cb + xb + 1];
                        for (int p = st + s; p < en; p += SEG) EVAL_BODY(p, ins_fast)
                    } else {
                        if (cx - 2 >= 0) {
                            const int st = cstart[cb + cx - 2], en = cstart[cb + cx - 1];
                            for (int p = st + s; p < en; p += SEG) EVAL_BODY(p, ins_fast)
                        }
                        if (cx + 2 <= GD - 1) {
                            const int st = cstart[cb + cx + 2], en = cstart[cb + cx + 3];
                            for (int p = st + s; p < en; p += SEG) EVAL_BODY(p, ins_fast)
                        }
                    }
                }
                merge_group(b0, b1, b2);

                // ring >=3 exact d2 >= (2h)^2 = 0.0625; else brute-force (dedup'd)
                have3 = (b2 != ~0ull);
                b2d = unmono((uint32_t)(b2 >> 32));
                if (!(have3 && (b2d + 1e-4f < 0.0625f))) {
                    for (int p = s; p < NXP; p += SEG) EVAL_BODY(p, ins_dedup)
                    merge_group(b0, b1, b2);
                }
            }
        }
#undef EVAL_BODY

        // epilogue (all 8 lanes hold the identical top-3)
        const int j[3] = { (int)(uint32_t)b0, (int)(uint32_t)b1, (int)(uint32_t)b2 };
        float w[3];
        #pragma unroll
        for (int i = 0; i < 3; ++i) {
            const int jj = j[i];
            const float ax = pos_x[jj*3+0], ay = pos_x[jj*3+1], az = pos_x[jj*3+2];
            const float dx = __fsub_rn(ax, y0);
            const float dy = __fsub_rn(ay, y1);
            const float dz = __fsub_rn(az, y2);
            const float sq = __fadd_rn(__fadd_rn(__fmul_rn(dx, dx), __fmul_rn(dy, dy)),
                                       __fmul_rn(dz, dz));
            w[i] = 1.0f / fmaxf(sq, 1e-16f);
        }
        const float inv_den = 1.0f / __fadd_rn(__fadd_rn(w[0], w[1]), w[2]);

        // lane s handles channels [2s, 2s+2): one float2 per neighbor (coalesced)
        const float2* x2 = (const float2*)x;   // row stride = 8 float2
        float2* o2 = (float2*)out;
        const float2 a = x2[j[0]*8 + s];
        const float2 b = x2[j[1]*8 + s];
        const float2 c = x2[j[2]*8 + s];
        float2 rr;
        rr.x = (w[0]*a.x + w[1]*b.x + w[2]*c.x) * inv_den;
        rr.y = (w[0]*a.y + w[1]*b.y + w[2]*c.y) * inv_den;
        o2[q*8 + s] = rr;
    }
}

extern "C" void kernel_launch(void* const* d_in, const int* in_sizes, int n_in,
                              void* d_out, int out_size, void* d_ws, size_t ws_size,
                              hipStream_t stream) {
    const float* x     = (const float*)d_in[0];  // [2048, 16]
    const float* pos_x = (const float*)d_in[1];  // [2048, 3]
    const float* pos_y = (const float*)d_in[2];  // [65536, 3]
    // d_in[3] is k (==3), hardcoded

    float* out = (float*)d_out;
    const int ny = in_sizes[2] / 3;  // 65536

    float4* wspt   = (float4*)((char*)d_ws + WS_SPT);
    int*    wsidx  = (int*)   ((char*)d_ws + WS_SIDX);
    int*    wcst   = (int*)   ((char*)d_ws + WS_CST);

    build_grid<<<1, BBLK, 0, stream>>>(pos_x, wspt, wsidx, wcst);

    knn_query<<<QGRID, QBLK, 0, stream>>>(x, pos_x, pos_y, wspt, wsidx, wcst, out, ny);
}